// Round 4
// baseline (1035.715 us; speedup 1.0000x reference)
//
#include <hip/hip_runtime.h>
#include <hip/hip_bf16.h>

// Sizes (fixed by the problem)
constexpr int H  = 16;
constexpr int HD = 64;
constexpr int D  = 1024;
constexpr int B  = 4;
constexpr int L  = 1024;
constexpr int P  = 2047;
constexpr int Pp = 2048;          // padded pos rows (row 2047 = zeros)
constexpr int M  = B * L;         // 4096
constexpr long OUT_ELEMS = (long)B * L * D;          // 4,194,304
constexpr float SCALE = 0.125f;   // 1/sqrt(64)

typedef __attribute__((ext_vector_type(8))) short  bf16x8;
typedef __attribute__((ext_vector_type(4))) float  f32x4;

#define MFMA(a, b, c) __builtin_amdgcn_mfma_f32_16x16x32_bf16((a), (b), (c), 0, 0, 0)

__device__ __forceinline__ unsigned short f2bf(float f) {
    __hip_bfloat16 h = __float2bfloat16(f);
    return __builtin_bit_cast(unsigned short, h);
}
__device__ __forceinline__ float bf2f(unsigned short u) {
    unsigned int v = ((unsigned int)u) << 16;
    return __builtin_bit_cast(float, v);
}

// ---------------------------------------------------------------------------
// f32 -> bf16 convert (4 elems/thread); indices >= nvalid write zero.
__global__ void cvt_kernel(const float* __restrict__ in, unsigned short* __restrict__ out,
                           long nvalid, long ntotal) {
    long i = ((long)blockIdx.x * blockDim.x + threadIdx.x) * 4;
    if (i >= ntotal) return;
    if (i < nvalid) {  // nvalid % 4 == 0 for all our calls
        float4 v = *(const float4*)(in + i);
        out[i + 0] = f2bf(v.x);
        out[i + 1] = f2bf(v.y);
        out[i + 2] = f2bf(v.z);
        out[i + 3] = f2bf(v.w);
    } else {
        out[i + 0] = 0; out[i + 1] = 0; out[i + 2] = 0; out[i + 3] = 0;
    }
}

// ---------------------------------------------------------------------------
// W[k][n] f32 (1024x1024) -> Wt[n][k] bf16 (transposed)
__global__ void wtrans_kernel(const float* __restrict__ W, unsigned short* __restrict__ Wt) {
    __shared__ float t[32][33];
    int n0 = blockIdx.x * 32, k0 = blockIdx.y * 32;
    int tx = threadIdx.x, ty = threadIdx.y;  // (32, 8)
#pragma unroll
    for (int s = 0; s < 4; ++s)
        t[ty + s * 8][tx] = W[(long)(k0 + ty + s * 8) * D + n0 + tx];
    __syncthreads();
#pragma unroll
    for (int s = 0; s < 4; ++s)
        Wt[(long)(n0 + ty + s * 8) * D + k0 + tx] = f2bf(t[tx][ty + s * 8]);
}

// ---------------------------------------------------------------------------
// V [4096][1024] bf16 -> Vt [B*H*HD][L] bf16  (Vt[(bh*64+d)][l] = V[b*1024+l][h*64+d])
__global__ void vtrans_kernel(const unsigned short* __restrict__ Vb, unsigned short* __restrict__ Vt) {
    __shared__ unsigned short t[64][65];
    int b = blockIdx.z, h = blockIdx.y, l0 = blockIdx.x * 64;
    int tx = threadIdx.x & 63, ty = threadIdx.x >> 6;  // 256 thr: ty 0..3
#pragma unroll
    for (int s = 0; s < 16; ++s) {
        int l = s * 4 + ty;
        t[l][tx] = Vb[(long)(b * L + l0 + l) * D + h * HD + tx];
    }
    __syncthreads();
#pragma unroll
    for (int s = 0; s < 16; ++s) {
        int d = s * 4 + ty;
        Vt[(long)((b * H + h) * HD + d) * L + l0 + tx] = t[tx][d];
    }
}

// ---------------------------------------------------------------------------
// Generic C = A(bf16 MxK, row-major contiguous k) @ Bt(bf16 NxK)ᵀ [+ bias]
// MODE 0: f32 out + bias; 1: bf16 out + bias; 2: bf16 out, no bias. N=K=1024.
template <int MODE>
__global__ __launch_bounds__(256) void gemm_bt(const unsigned short* __restrict__ A,
                                               const unsigned short* __restrict__ Bt,
                                               const float* __restrict__ bias,
                                               float* __restrict__ outF,
                                               unsigned short* __restrict__ outB) {
    int wave = threadIdx.x >> 6;
    int lane = threadIdx.x & 63;
    int r = lane & 15, g = lane >> 4;
    int row0 = blockIdx.x * 64 + wave * 16;
    int col0 = blockIdx.y * 64;
    f32x4 acc[4] = {};
    const long arow = (long)(row0 + r) * D;
    for (int ks = 0; ks < D; ks += 32) {
        bf16x8 a = *(const bf16x8*)(A + arow + ks + g * 8);
#pragma unroll
        for (int c = 0; c < 4; ++c) {
            bf16x8 b = *(const bf16x8*)(Bt + (long)(col0 + c * 16 + r) * D + ks + g * 8);
            acc[c] = MFMA(a, b, acc[c]);
        }
    }
#pragma unroll
    for (int c = 0; c < 4; ++c) {
        int col = col0 + c * 16 + r;
        float bv = (MODE != 2) ? bias[col] : 0.f;
#pragma unroll
        for (int i = 0; i < 4; ++i) {
            long row = row0 + g * 4 + i;
            float v = acc[c][i] + bv;
            if (MODE == 0) outF[row * D + col] = v;
            else           outB[row * D + col] = f2bf(v);
        }
    }
}

// ---------------------------------------------------------------------------
// Fused scores + softmax + probs-write + P@V.  4 waves/block, 16 q-rows/wave.
// Two sweeps over the K/pos panels: sweep 0 accumulates rowsum of exp(s)
// (|s| < ~5 so no max subtraction needed); sweep 1 recomputes, writes
// normalized probs (fp32, write-once) and accumulates ctx = P@V via an
// XOR-swizzled LDS transpose of the P tile into MFMA A-fragments.
template <int OUT>
__device__ __forceinline__ void attn_sweep(
    int b, int h, int l0, int r, int g,
    const bf16x8* aqu, const bf16x8* aqv,
    const unsigned short* __restrict__ Kb, const unsigned short* __restrict__ posb,
    const unsigned short* __restrict__ Vt,
    float (*Es)[80], unsigned short* Ps,
    float* rsum, const float* inv, float* __restrict__ probs, f32x4* ctxacc)
{
    const long Srow0 = ((long)((b * H + h) * L + l0)) * L;
    for (int mc = 0; mc < L; mc += 64) {
        int rp0 = (L - 1) + mc - l0 - 15;  // in [0,1968]; +79 <= 2047 (zero pad row)
        // E band: E[i][c] = qv[l0+i] . pos[rp0+c], c in [0,80)
        f32x4 eacc[5];
#pragma unroll
        for (int t = 0; t < 5; ++t) eacc[t] = f32x4{0.f, 0.f, 0.f, 0.f};
#pragma unroll
        for (int ks = 0; ks < 2; ++ks)
#pragma unroll
            for (int t = 0; t < 5; ++t) {
                bf16x8 bp = *(const bf16x8*)(posb + (long)(rp0 + t * 16 + r) * D + h * HD + ks * 32 + g * 8);
                eacc[t] = MFMA(aqv[ks], bp, eacc[t]);
            }
#pragma unroll
        for (int t = 0; t < 5; ++t)
#pragma unroll
            for (int i = 0; i < 4; ++i)
                Es[g * 4 + i][t * 16 + r] = eacc[t][i];
        asm volatile("s_waitcnt lgkmcnt(0)" ::: "memory");  // per-wave LDS RAW fence
        __builtin_amdgcn_sched_barrier(0);

#pragma unroll
        for (int t = 0; t < 4; ++t) {
            f32x4 acc = {0.f, 0.f, 0.f, 0.f};
#pragma unroll
            for (int ks = 0; ks < 2; ++ks) {
                bf16x8 bk = *(const bf16x8*)(Kb + (long)(b * L + mc + t * 16 + r) * D + h * HD + ks * 32 + g * 8);
                acc = MFMA(aqu[ks], bk, acc);
            }
            int j = t * 16 + r;
#pragma unroll
            for (int i = 0; i < 4; ++i) {
                int il = g * 4 + i;
                float s = (acc[i] + Es[il][j - il + 15]) * SCALE;
                float e = __expf(s);
                if (OUT) {
                    float p = e * inv[i];
                    probs[Srow0 + (long)il * L + mc + j] = p;
                    int elem = il * 64 + j;
                    Ps[elem ^ ((il & 7) << 3)] = f2bf(p);  // XOR-swizzled bf16 tile
                } else {
                    rsum[i] += e;
                }
            }
        }
        if (OUT) {
            asm volatile("s_waitcnt lgkmcnt(0)" ::: "memory");
            __builtin_amdgcn_sched_barrier(0);
#pragma unroll
            for (int kh = 0; kh < 2; ++kh) {
                int elem = (r * 64 + kh * 32 + g * 8) ^ ((r & 7) << 3);
                bf16x8 pa = *(const bf16x8*)(Ps + elem);  // conflict-free ds_read_b128
#pragma unroll
                for (int c = 0; c < 4; ++c) {
                    bf16x8 bv = *(const bf16x8*)(Vt + (long)((b * H + h) * HD + c * 16 + r) * L + mc + kh * 32 + g * 8);
                    ctxacc[c] = MFMA(pa, bv, ctxacc[c]);
                }
            }
        }
        asm volatile("" ::: "memory");  // keep this chunk's LDS reads before next chunk's writes
    }
}

__global__ __launch_bounds__(256) void fused_attn(
    const unsigned short* __restrict__ Qb, const unsigned short* __restrict__ Kb,
    const unsigned short* __restrict__ posb, const float* __restrict__ pu,
    const float* __restrict__ pv, const unsigned short* __restrict__ Vt,
    float* __restrict__ probs, unsigned short* __restrict__ ctxb)
{
    __shared__ float Es[4][16][80];
    __shared__ unsigned short Ps[4][1024];
    int tid = threadIdx.x;
    int wave = tid >> 6, lane = tid & 63;
    int r = lane & 15, g = lane >> 4;

    // XCD-bijective, h-major block swizzle: each XCD owns 2 h's worth of K/V/pos.
    int lin = blockIdx.x;                       // 0..1023
    int swz = (lin & 7) * 128 + (lin >> 3);
    int h = swz >> 6;
    int b = (swz >> 4) & 3;
    int l0 = (swz & 15) * 64 + wave * 16;

    // Q fragments with u/v biases folded in
    bf16x8 aqu[2], aqv[2];
    long qoff = (long)(b * L + l0 + r) * D + h * HD;
#pragma unroll
    for (int ks = 0; ks < 2; ++ks) {
        bf16x8 q = *(const bf16x8*)(Qb + qoff + ks * 32 + g * 8);
        bf16x8 u, v;
#pragma unroll
        for (int e = 0; e < 8; ++e) {
            float qf = bf2f((unsigned short)q[e]);
            int d = ks * 32 + g * 8 + e;
            u[e] = (short)f2bf(qf + pu[h * HD + d]);
            v[e] = (short)f2bf(qf + pv[h * HD + d]);
        }
        aqu[ks] = u; aqv[ks] = v;
    }

    float rsum[4] = {0.f, 0.f, 0.f, 0.f};
    f32x4 ctxacc[4] = {};

    attn_sweep<0>(b, h, l0, r, g, aqu, aqv, Kb, posb, Vt,
                  Es[wave], Ps[wave], rsum, nullptr, probs, ctxacc);

    // combine partial sums across the 16 lanes sharing each row (r bits only)
    float inv[4];
#pragma unroll
    for (int i = 0; i < 4; ++i) {
        float s = rsum[i];
        for (int off = 1; off < 16; off <<= 1) s += __shfl_xor(s, off);
        inv[i] = 1.0f / s;
    }

    attn_sweep<1>(b, h, l0, r, g, aqu, aqv, Kb, posb, Vt,
                  Es[wave], Ps[wave], rsum, inv, probs, ctxacc);

    // store ctx (bf16) for the output projection
#pragma unroll
    for (int c = 0; c < 4; ++c)
#pragma unroll
        for (int i = 0; i < 4; ++i)
            ctxb[(long)(b * L + l0 + g * 4 + i) * D + h * HD + c * 16 + r] = f2bf(ctxacc[c][i]);
}

// ---------------------------------------------------------------------------
extern "C" void kernel_launch(void* const* d_in, const int* in_sizes, int n_in,
                              void* d_out, int out_size, void* d_ws, size_t ws_size,
                              hipStream_t stream) {
    const float* hs   = (const float*)d_in[0];
    const float* rpe  = (const float*)d_in[1];
    const float* Wq   = (const float*)d_in[2];
    const float* bq   = (const float*)d_in[3];
    const float* Wk   = (const float*)d_in[4];
    const float* bk   = (const float*)d_in[5];
    const float* Wv   = (const float*)d_in[6];
    const float* bv   = (const float*)d_in[7];
    const float* Wpos = (const float*)d_in[8];
    const float* pu   = (const float*)d_in[9];
    const float* pv   = (const float*)d_in[10];
    const float* Wo   = (const float*)d_in[11];
    const float* bo   = (const float*)d_in[12];

    char* ws = (char*)d_ws;
    size_t off = 0;
    auto alloc = [&](size_t bytes) -> void* {
        void* p = ws + off;
        off += (bytes + 255) & ~(size_t)255;
        return p;
    };
    unsigned short* Xb   = (unsigned short*)alloc((size_t)M * D * 2);
    unsigned short* Wqt  = (unsigned short*)alloc((size_t)D * D * 2);
    unsigned short* Wkt  = (unsigned short*)alloc((size_t)D * D * 2);
    unsigned short* Wvt  = (unsigned short*)alloc((size_t)D * D * 2);
    unsigned short* Wpot = (unsigned short*)alloc((size_t)D * D * 2);
    unsigned short* Wot  = (unsigned short*)alloc((size_t)D * D * 2);
    unsigned short* rpb  = (unsigned short*)alloc((size_t)Pp * D * 2);
    unsigned short* posb = (unsigned short*)alloc((size_t)Pp * D * 2);
    unsigned short* Qb   = (unsigned short*)alloc((size_t)M * D * 2);
    unsigned short* Kb   = (unsigned short*)alloc((size_t)M * D * 2);
    unsigned short* Vb   = (unsigned short*)alloc((size_t)M * D * 2);
    unsigned short* Vt   = (unsigned short*)alloc((size_t)M * D * 2);
    unsigned short* ctxb = (unsigned short*)alloc((size_t)M * D * 2);

    float* outp  = (float*)d_out;
    float* probs = outp + OUT_ELEMS;

    // converts / transposes
    cvt_kernel<<<(M * D) / 1024, 256, 0, stream>>>(hs, Xb, (long)M * D, (long)M * D);
    cvt_kernel<<<(Pp * D) / 1024, 256, 0, stream>>>(rpe, rpb, (long)P * D, (long)Pp * D);
    dim3 wtg(32, 32), wtb(32, 8);
    wtrans_kernel<<<wtg, wtb, 0, stream>>>(Wq, Wqt);
    wtrans_kernel<<<wtg, wtb, 0, stream>>>(Wk, Wkt);
    wtrans_kernel<<<wtg, wtb, 0, stream>>>(Wv, Wvt);
    wtrans_kernel<<<wtg, wtb, 0, stream>>>(Wpos, Wpot);
    wtrans_kernel<<<wtg, wtb, 0, stream>>>(Wo, Wot);

    // projections
    gemm_bt<1><<<dim3(M / 64, D / 64), 256, 0, stream>>>(Xb, Wqt, bq, nullptr, Qb);
    gemm_bt<1><<<dim3(M / 64, D / 64), 256, 0, stream>>>(Xb, Wkt, bk, nullptr, Kb);
    gemm_bt<1><<<dim3(M / 64, D / 64), 256, 0, stream>>>(Xb, Wvt, bv, nullptr, Vb);
    gemm_bt<2><<<dim3(Pp / 64, D / 64), 256, 0, stream>>>(rpb, Wpot, nullptr, nullptr, posb);
    vtrans_kernel<<<dim3(L / 64, H, B), 256, 0, stream>>>(Vb, Vt);

    // fused scores + softmax + probs + P@V
    fused_attn<<<B * H * (L / 64), 256, 0, stream>>>(Qb, Kb, posb, pu, pv, Vt, probs, ctxb);

    // out = ctx @ Wo + bo
    gemm_bt<0><<<dim3(M / 64, D / 64), 256, 0, stream>>>(ctxb, Wot, bo, outp, nullptr);
}

// Round 12
// 861.083 us; speedup vs baseline: 1.2028x; 1.2028x over previous
//
#include <hip/hip_runtime.h>
#include <hip/hip_bf16.h>

// Sizes (fixed by the problem)
constexpr int H  = 16;
constexpr int HD = 64;
constexpr int D  = 1024;
constexpr int B  = 4;
constexpr int L  = 1024;
constexpr int P  = 2047;
constexpr int Pp = 2048;          // padded pos rows (row 2047 = zeros)
constexpr int M  = B * L;         // 4096
constexpr long OUT_ELEMS = (long)B * L * D;          // 4,194,304
constexpr float SCALE = 0.125f;   // 1/sqrt(64)

typedef __attribute__((ext_vector_type(8))) short  bf16x8;
typedef __attribute__((ext_vector_type(4))) float  f32x4;

#define MFMA(a, b, c) __builtin_amdgcn_mfma_f32_16x16x32_bf16((a), (b), (c), 0, 0, 0)

__device__ __forceinline__ unsigned short f2bf(float f) {
    __hip_bfloat16 h = __float2bfloat16(f);
    return __builtin_bit_cast(unsigned short, h);
}
__device__ __forceinline__ float bf2f(unsigned short u) {
    unsigned int v = ((unsigned int)u) << 16;
    return __builtin_bit_cast(float, v);
}

// ---------------------------------------------------------------------------
// f32 -> bf16 convert (4 elems/thread); indices >= nvalid write zero.
__global__ void cvt_kernel(const float* __restrict__ in, unsigned short* __restrict__ out,
                           long nvalid, long ntotal) {
    long i = ((long)blockIdx.x * blockDim.x + threadIdx.x) * 4;
    if (i >= ntotal) return;
    if (i < nvalid) {  // nvalid % 4 == 0 for all our calls
        float4 v = *(const float4*)(in + i);
        out[i + 0] = f2bf(v.x);
        out[i + 1] = f2bf(v.y);
        out[i + 2] = f2bf(v.z);
        out[i + 3] = f2bf(v.w);
    } else {
        out[i + 0] = 0; out[i + 1] = 0; out[i + 2] = 0; out[i + 3] = 0;
    }
}

// ---------------------------------------------------------------------------
// W[k][n] f32 (1024x1024) -> Wt[n][k] bf16 (transposed)
__global__ void wtrans_kernel(const float* __restrict__ W, unsigned short* __restrict__ Wt) {
    __shared__ float t[32][33];
    int n0 = blockIdx.x * 32, k0 = blockIdx.y * 32;
    int tx = threadIdx.x, ty = threadIdx.y;  // (32, 8)
#pragma unroll
    for (int s = 0; s < 4; ++s)
        t[ty + s * 8][tx] = W[(long)(k0 + ty + s * 8) * D + n0 + tx];
    __syncthreads();
#pragma unroll
    for (int s = 0; s < 4; ++s)
        Wt[(long)(n0 + ty + s * 8) * D + k0 + tx] = f2bf(t[tx][ty + s * 8]);
}

// ---------------------------------------------------------------------------
// V [4096][1024] bf16 -> Vt [B*H*HD][L] bf16  (Vt[(bh*64+d)][l] = V[b*1024+l][h*64+d])
__global__ void vtrans_kernel(const unsigned short* __restrict__ Vb, unsigned short* __restrict__ Vt) {
    __shared__ unsigned short t[64][65];
    int b = blockIdx.z, h = blockIdx.y, l0 = blockIdx.x * 64;
    int tx = threadIdx.x & 63, ty = threadIdx.x >> 6;  // 256 thr: ty 0..3
#pragma unroll
    for (int s = 0; s < 16; ++s) {
        int l = s * 4 + ty;
        t[l][tx] = Vb[(long)(b * L + l0 + l) * D + h * HD + tx];
    }
    __syncthreads();
#pragma unroll
    for (int s = 0; s < 16; ++s) {
        int d = s * 4 + ty;
        Vt[(long)((b * H + h) * HD + d) * L + l0 + tx] = t[tx][d];
    }
}

// ---------------------------------------------------------------------------
// Generic C = A(bf16 MxK, row-major contiguous k) @ Bt(bf16 NxK)^T [+ bias]
// MODE 0: f32 out + bias; 1: bf16 out + bias; 2: bf16 out, no bias. N=K=1024.
template <int MODE>
__global__ __launch_bounds__(256) void gemm_bt(const unsigned short* __restrict__ A,
                                               const unsigned short* __restrict__ Bt,
                                               const float* __restrict__ bias,
                                               float* __restrict__ outF,
                                               unsigned short* __restrict__ outB) {
    int wave = threadIdx.x >> 6;
    int lane = threadIdx.x & 63;
    int r = lane & 15, g = lane >> 4;
    int row0 = blockIdx.x * 64 + wave * 16;
    int col0 = blockIdx.y * 64;
    f32x4 acc[4] = {};
    const long arow = (long)(row0 + r) * D;
    for (int ks = 0; ks < D; ks += 32) {
        bf16x8 a = *(const bf16x8*)(A + arow + ks + g * 8);
#pragma unroll
        for (int c = 0; c < 4; ++c) {
            bf16x8 b = *(const bf16x8*)(Bt + (long)(col0 + c * 16 + r) * D + ks + g * 8);
            acc[c] = MFMA(a, b, acc[c]);
        }
    }
#pragma unroll
    for (int c = 0; c < 4; ++c) {
        int col = col0 + c * 16 + r;
        float bv = (MODE != 2) ? bias[col] : 0.f;
#pragma unroll
        for (int i = 0; i < 4; ++i) {
            long row = row0 + g * 4 + i;
            float v = acc[c][i] + bv;
            if (MODE == 0) outF[row * D + col] = v;
            else           outB[row * D + col] = f2bf(v);
        }
    }
}

// ---------------------------------------------------------------------------
// Single-sweep fused scores + softmax + probs-write + P@V.
// Block = 1024 threads = 16 waves = 4 row-tiles (wr) x 4 mc-quarters (wq)
// over a 64-row q-tile of one (b, h). Each wave: 16 q-rows x 256 k-cols.
// Phase 1: scores -> exp(s) kept in registers as PACKED bf16 pairs (pPk,
// 32 VGPRs) + partial rowsums in f32.
// Phase 2 (after block rowsum combine): normalize from registers, write
// probs once, stage P tile in LDS (XOR-swizzled), accumulate partial ctx.
// Phase 3: combine partial ctx across wq via LDS, write ctx bf16.
// No max-subtraction needed: |s| < ~6 so exp in f32 is safe.
// launch_bounds(1024,4): 128-VGPR cap -> 16 waves/CU; (1024,8) would force
// a 64-VGPR cap (m69: 32 waves/CU needs <=64) and spill pPk to scratch.
__global__ __launch_bounds__(1024, 4) void fused_attn(
    const unsigned short* __restrict__ Qb, const unsigned short* __restrict__ Kb,
    const unsigned short* __restrict__ posb, const float* __restrict__ pu,
    const float* __restrict__ pv, const unsigned short* __restrict__ Vt,
    float* __restrict__ probs, unsigned short* __restrict__ ctxb)
{
    // per-wave scratch: Es_t band (80 cols x stride 20, bf16) unioned with Ps
    // (Es is dead after phase 1; Ps used in phase 2 only)
    __shared__ __align__(16) unsigned short scratch[16][1600];  // 51.2 KB
    __shared__ __align__(16) float rs[64][4];                   // 1 KB
    __shared__ __align__(16) float ctxcomb[4][16][68];          // 17.4 KB (padded stride)

    int tid = threadIdx.x;
    int wave = tid >> 6, lane = tid & 63;
    int r = lane & 15, g = lane >> 4;
    int wq = wave & 3, wr = wave >> 2;

    // XCD-bijective, h-major block swizzle: each XCD owns 2 h's K/V/pos (~2.5MB in L2)
    int lin = blockIdx.x;                       // 0..1023
    int swz = (lin & 7) * 128 + (lin >> 3);
    int h = swz >> 6;
    int b = (swz >> 4) & 3;
    int l0base = (swz & 15) * 64;
    int l0 = l0base + wr * 16;

    unsigned short* Es = scratch[wave];
    unsigned short* Ps = scratch[wave];
    const int hHD = h * HD;

    // Q fragments with u/v biases folded in (this wave's 16 rows)
    bf16x8 aqu[2], aqv[2];
    {
        long qoff = (long)(b * L + l0 + r) * D + hHD;
#pragma unroll
        for (int ks = 0; ks < 2; ++ks) {
            bf16x8 q = *(const bf16x8*)(Qb + qoff + ks * 32 + g * 8);
            bf16x8 u, v;
#pragma unroll
            for (int e = 0; e < 8; ++e) {
                float qf = bf2f((unsigned short)q[e]);
                int d = ks * 32 + g * 8 + e;
                u[e] = (short)f2bf(qf + pu[hHD + d]);
                v[e] = (short)f2bf(qf + pv[hHD + d]);
            }
            aqu[ks] = u; aqv[ks] = v;
        }
    }

    float rsum[4] = {0.f, 0.f, 0.f, 0.f};
    unsigned int pPk[4][4][2];   // packed bf16 exp(s): [chunk][t][pair], static idx
    const long KbRow = (long)(b * L) * D + hHD;

    // ---- Phase 1: scores + exp, kept in registers (packed bf16) ----
#pragma unroll
    for (int cc = 0; cc < 4; ++cc) {
        int mc = wq * 256 + cc * 64;
        int rp0 = (L - 1) + mc - l0 - 15;   // in [0,1968]; +79 <= 2047 (zero pad row)
        f32x4 eacc[5] = {};
#pragma unroll
        for (int ks = 0; ks < 2; ++ks)
#pragma unroll
            for (int t = 0; t < 5; ++t) {
                bf16x8 bp = *(const bf16x8*)(posb + (long)(rp0 + t * 16 + r) * D + hHD + ks * 32 + g * 8);
                eacc[t] = MFMA(aqv[ks], bp, eacc[t]);
            }
        // store E transposed [c][il], bf16, stride 20 (b64 writes, 8B aligned)
#pragma unroll
        for (int t = 0; t < 5; ++t) {
            ushort4 pk;
            pk.x = f2bf(eacc[t][0]); pk.y = f2bf(eacc[t][1]);
            pk.z = f2bf(eacc[t][2]); pk.w = f2bf(eacc[t][3]);
            *(ushort4*)(Es + (t * 16 + r) * 20 + g * 4) = pk;
        }
        asm volatile("s_waitcnt lgkmcnt(0)" ::: "memory");  // per-wave LDS RAW fence
        __builtin_amdgcn_sched_barrier(0);

#pragma unroll
        for (int t = 0; t < 4; ++t) {
            f32x4 acc = {};
#pragma unroll
            for (int ks = 0; ks < 2; ++ks) {
                bf16x8 bk = *(const bf16x8*)(Kb + KbRow + (long)(mc + t * 16 + r) * D + ks * 32 + g * 8);
                acc = MFMA(aqu[ks], bk, acc);
            }
            float ev[4];
#pragma unroll
            for (int i = 0; i < 4; ++i) {
                int il = g * 4 + i;
                int c = t * 16 + r - il + 15;       // in [0,78]
                float s = (acc[i] + bf2f(Es[c * 20 + il])) * SCALE;
                float e = __expf(s);
                rsum[i] += e;
                ev[i] = e;
            }
            pPk[cc][t][0] = ((unsigned)f2bf(ev[1]) << 16) | f2bf(ev[0]);
            pPk[cc][t][1] = ((unsigned)f2bf(ev[3]) << 16) | f2bf(ev[2]);
        }
        asm volatile("" ::: "memory");  // keep Es reads before next chunk's writes
    }

    // ---- block rowsum combine ----
#pragma unroll
    for (int i = 0; i < 4; ++i) {
        float s = rsum[i];
        s += __shfl_xor(s, 1); s += __shfl_xor(s, 2);
        s += __shfl_xor(s, 4); s += __shfl_xor(s, 8);
        rsum[i] = s;
    }
    if (r == 0) {
#pragma unroll
        for (int i = 0; i < 4; ++i) rs[wr * 16 + g * 4 + i][wq] = rsum[i];
    }
    __syncthreads();
    float inv[4];
#pragma unroll
    for (int i = 0; i < 4; ++i) {
        float4 v = *(const float4*)&rs[wr * 16 + g * 4 + i][0];  // broadcast read
        inv[i] = 1.0f / (v.x + v.y + v.z + v.w);
    }

    // ---- Phase 2: normalize, write probs, PV ----
    f32x4 ctxacc[4] = {};
    const long ProwBase = ((long)((b * H + h) * L + l0)) * L;
    const long VtBase = (long)((b * H + h) * HD) * L;
#pragma unroll
    for (int cc = 0; cc < 4; ++cc) {
        int mc = wq * 256 + cc * 64;
#pragma unroll
        for (int t = 0; t < 4; ++t) {
            float ev[4];
            ev[0] = bf2f((unsigned short)(pPk[cc][t][0] & 0xffff));
            ev[1] = bf2f((unsigned short)(pPk[cc][t][0] >> 16));
            ev[2] = bf2f((unsigned short)(pPk[cc][t][1] & 0xffff));
            ev[3] = bf2f((unsigned short)(pPk[cc][t][1] >> 16));
#pragma unroll
            for (int i = 0; i < 4; ++i) {
                int il = g * 4 + i;
                int j = t * 16 + r;
                float p = ev[i] * inv[i];
                probs[ProwBase + (long)il * L + mc + j] = p;
                int elem = il * 64 + j;
                Ps[elem ^ ((il & 7) << 3)] = f2bf(p);   // XOR-swizzled bf16 tile
            }
        }
        asm volatile("s_waitcnt lgkmcnt(0)" ::: "memory");
        __builtin_amdgcn_sched_barrier(0);
#pragma unroll
        for (int kh = 0; kh < 2; ++kh) {
            int elem = (r * 64 + kh * 32 + g * 8) ^ ((r & 7) << 3);
            bf16x8 pa = *(const bf16x8*)(Ps + elem);    // conflict-free b128
#pragma unroll
            for (int c = 0; c < 4; ++c) {
                bf16x8 bv = *(const bf16x8*)(Vt + VtBase + (long)(c * 16 + r) * L + mc + kh * 32 + g * 8);
                ctxacc[c] = MFMA(pa, bv, ctxacc[c]);
            }
        }
        asm volatile("" ::: "memory");
    }

    // ---- Phase 3: combine partial ctx across wq, write ctx bf16 ----
    if (wq == 0) {
#pragma unroll
        for (int c = 0; c < 4; ++c)
#pragma unroll
            for (int i = 0; i < 4; ++i)
                ctxcomb[wr][g * 4 + i][c * 16 + r] = ctxacc[c][i];
    }
    __syncthreads();
#pragma unroll
    for (int q = 1; q < 4; ++q) {
        if (wq == q) {
#pragma unroll
            for (int c = 0; c < 4; ++c)
#pragma unroll
                for (int i = 0; i < 4; ++i)
                    ctxcomb[wr][g * 4 + i][c * 16 + r] += ctxacc[c][i];
        }
        __syncthreads();
    }
    {
        int row = lane >> 2;             // 0..15
        int colg = (lane & 3) * 4;       // 0,4,8,12
        float4 v = *(const float4*)&ctxcomb[wr][row][wq * 16 + colg];
        ushort4 o;
        o.x = f2bf(v.x); o.y = f2bf(v.y); o.z = f2bf(v.z); o.w = f2bf(v.w);
        *(ushort4*)(ctxb + (long)(b * L + l0base + wr * 16 + row) * D + hHD + wq * 16 + colg) = o;
    }
}

// ---------------------------------------------------------------------------
extern "C" void kernel_launch(void* const* d_in, const int* in_sizes, int n_in,
                              void* d_out, int out_size, void* d_ws, size_t ws_size,
                              hipStream_t stream) {
    const float* hs   = (const float*)d_in[0];
    const float* rpe  = (const float*)d_in[1];
    const float* Wq   = (const float*)d_in[2];
    const float* bq   = (const float*)d_in[3];
    const float* Wk   = (const float*)d_in[4];
    const float* bk   = (const float*)d_in[5];
    const float* Wv   = (const float*)d_in[6];
    const float* bv   = (const float*)d_in[7];
    const float* Wpos = (const float*)d_in[8];
    const float* pu   = (const float*)d_in[9];
    const float* pv   = (const float*)d_in[10];
    const float* Wo   = (const float*)d_in[11];
    const float* bo   = (const float*)d_in[12];

    char* ws = (char*)d_ws;
    size_t off = 0;
    auto alloc = [&](size_t bytes) -> void* {
        void* p = ws + off;
        off += (bytes + 255) & ~(size_t)255;
        return p;
    };
    unsigned short* Xb   = (unsigned short*)alloc((size_t)M * D * 2);
    unsigned short* Wqt  = (unsigned short*)alloc((size_t)D * D * 2);
    unsigned short* Wkt  = (unsigned short*)alloc((size_t)D * D * 2);
    unsigned short* Wvt  = (unsigned short*)alloc((size_t)D * D * 2);
    unsigned short* Wpot = (unsigned short*)alloc((size_t)D * D * 2);
    unsigned short* Wot  = (unsigned short*)alloc((size_t)D * D * 2);
    unsigned short* rpb  = (unsigned short*)alloc((size_t)Pp * D * 2);
    unsigned short* posb = (unsigned short*)alloc((size_t)Pp * D * 2);
    unsigned short* Qb   = (unsigned short*)alloc((size_t)M * D * 2);
    unsigned short* Kb   = (unsigned short*)alloc((size_t)M * D * 2);
    unsigned short* Vb   = (unsigned short*)alloc((size_t)M * D * 2);
    unsigned short* Vt   = (unsigned short*)alloc((size_t)M * D * 2);
    unsigned short* ctxb = (unsigned short*)alloc((size_t)M * D * 2);

    float* outp  = (float*)d_out;
    float* probs = outp + OUT_ELEMS;

    // converts / transposes
    cvt_kernel<<<(M * D) / 1024, 256, 0, stream>>>(hs, Xb, (long)M * D, (long)M * D);
    cvt_kernel<<<(Pp * D) / 1024, 256, 0, stream>>>(rpe, rpb, (long)P * D, (long)Pp * D);
    dim3 wtg(32, 32), wtb(32, 8);
    wtrans_kernel<<<wtg, wtb, 0, stream>>>(Wq, Wqt);
    wtrans_kernel<<<wtg, wtb, 0, stream>>>(Wk, Wkt);
    wtrans_kernel<<<wtg, wtb, 0, stream>>>(Wv, Wvt);
    wtrans_kernel<<<wtg, wtb, 0, stream>>>(Wpos, Wpot);
    wtrans_kernel<<<wtg, wtb, 0, stream>>>(Wo, Wot);

    // projections
    gemm_bt<1><<<dim3(M / 64, D / 64), 256, 0, stream>>>(Xb, Wqt, bq, nullptr, Qb);
    gemm_bt<1><<<dim3(M / 64, D / 64), 256, 0, stream>>>(Xb, Wkt, bk, nullptr, Kb);
    gemm_bt<1><<<dim3(M / 64, D / 64), 256, 0, stream>>>(Xb, Wvt, bv, nullptr, Vb);
    gemm_bt<2><<<dim3(Pp / 64, D / 64), 256, 0, stream>>>(rpb, Wpot, nullptr, nullptr, posb);
    vtrans_kernel<<<dim3(L / 64, H, B), 256, 0, stream>>>(Vb, Vt);

    // fused scores + softmax + probs + P@V  (1024 blocks x 1024 threads)
    fused_attn<<<B * H * (L / 64), 1024, 0, stream>>>(Qb, Kb, posb, pu, pv, Vt, probs, ctxb);

    // out = ctx @ Wo + bo
    gemm_bt<0><<<dim3(M / 64, D / 64), 256, 0, stream>>>(ctxb, Wot, bo, outp, nullptr);
}